// Round 6
// baseline (246.451 us; speedup 1.0000x reference)
//
#include <hip/hip_runtime.h>
#include <cstddef>

#define D   64
#define L   128
#define NT  128            // 2 waves per block
#define ROWS 16            // one M=16 MFMA tile per block
#define XSS 132            // padded floats (mult of 4 keeps float4 alignment)
#define HBS 72             // shorts
#define NBLK 512           // 8192 / 16
#define LOG2E 1.4426950408889634f

typedef __attribute__((ext_vector_type(8))) short short8;
typedef __attribute__((ext_vector_type(4))) float floatx4;

__device__ __forceinline__ float fast_rcp(float x) {
#if defined(__has_builtin)
#if __has_builtin(__builtin_amdgcn_rcpf)
  return __builtin_amdgcn_rcpf(x);
#else
  return 1.0f / x;
#endif
#else
  return 1.0f / x;
#endif
}
__device__ __forceinline__ float ex2(float x) {
#if defined(__has_builtin)
#if __has_builtin(__builtin_amdgcn_exp2f)
  return __builtin_amdgcn_exp2f(x);
#else
  return __builtin_exp2f(x);
#endif
#else
  return __builtin_exp2f(x);
#endif
}
__device__ __forceinline__ float sig_plain(float x) {
  return fast_rcp(1.0f + ex2(-LOG2E * x));
}
__device__ __forceinline__ float tanh2(float G) {   // tanh(x), G = -2log2e*x
  return fmaf(2.0f, fast_rcp(1.0f + ex2(G)), -1.0f);
}
__device__ __forceinline__ unsigned short f2bf_rtne(float f) {
  unsigned int u = __float_as_uint(f);
  u += 0x7fffu + ((u >> 16) & 1u);
  return (unsigned short)(u >> 16);
}
__device__ __forceinline__ float bf2f(unsigned short s) {
  return __uint_as_float(((unsigned int)s) << 16);
}

// Persistent 16-row LSTM scan, 2-wave blocks (minimal sync domain, no
// cross-block MFMA contention: 512 blocks -> 1 wave/SIMD, block per SIMD-pair).
// Wave w owns d in [32w,32w+32) for all 4 gates (8 N-tiles, 8 cells/lane);
// elementwise in registers. 2-term MFMA split: A = bf16(h) (random error),
// B = W_hh hi+lo (exact). Gates prescaled for exp2; merged 2-rcp algebra.
__global__ __launch_bounds__(NT, 1)
void lstm_main(const float* __restrict__ x,
               const float* __restrict__ W_num,
               const float* __restrict__ b_num,
               const float* __restrict__ W_ih,
               const float* __restrict__ W_hh,
               const float* __restrict__ b_ih,
               const float* __restrict__ b_hh,
               const float* __restrict__ W_aout,
               const float* __restrict__ b_aout,
               const float* __restrict__ W_fh,
               const float* __restrict__ b_fh,
               const float* __restrict__ W_iouh,
               const float* __restrict__ b_iouh,
               const float* __restrict__ W_oout,
               const float* __restrict__ b_oout,
               float* __restrict__ acc_out,   // [0..63]=fc, [64..127]=hs, [128]=ticket
               float* __restrict__ out)
{
  __shared__ __align__(16) float xs[ROWS * XSS];       // 8.25 KB (x; later h/h_hat)
  __shared__ __align__(16) short hb[2][ROWS * HBS];    // 4.5 KB double-buffered bf16 h
  __shared__ float sacc[2 * D];
  __shared__ float hobj[D];
  __shared__ int   is_last;

  const int tid  = threadIdx.x;
  const int w    = tid >> 6;       // wave 0..1
  const int lane = tid & 63;
  const int quad = lane >> 4;
  const int c16  = lane & 15;
  const int k0   = blockIdx.x * ROWS;

  // ---- stage x tile (16 rows x 128), coalesced ----
  for (int i = tid; i < ROWS * (L / 4); i += NT) {
    int r = i >> 5, c4 = i & 31;
    float4 v = ((const float4*)(x + (size_t)(k0 + r) * L))[c4];
    float* dst = &xs[r * XSS + c4 * 4];
    dst[0] = v.x; dst[1] = v.y; dst[2] = v.z; dst[3] = v.w;
  }
  for (int i = tid; i < ROWS * HBS; i += NT) hb[0][i] = 0;

  // per-gate exp2 prescale (g-gate feeds tanh -> -2log2e)
  const float gscale[4] = {-LOG2E, -LOG2E, -2.0f * LOG2E, -LOG2E};

  // this wave's 8 N-tiles: n = g*2 + e covers gate g, d = (2w+e)*16 + c16
  // ---- rank-1 x-projection constants (prescaled) ----
  float An[8], Bc[8];
#pragma unroll
  for (int n = 0; n < 8; ++n) {
    int g = n >> 1, e = n & 1;
    int j = g * 64 + (2 * w + e) * 16 + c16;
    float a = 0.0f, b = b_ih[j] + b_hh[j];
    for (int ee = 0; ee < D; ++ee) {
      float wih = W_ih[(size_t)j * (2 * D) + ee];   // W_ih[:, :D]
      a = fmaf(W_num[ee], wih, a);
      b = fmaf(b_num[ee], wih, b);
    }
    An[n] = a * gscale[g]; Bc[n] = b * gscale[g];
  }

  // ---- W_hh B-fragments (prescaled, hi+lo exact, constant across steps) ----
  short8 Bhi[2][8], Blo[2][8];   // [kk][n]
#pragma unroll
  for (int kk = 0; kk < 2; ++kk) {
#pragma unroll
    for (int n = 0; n < 8; ++n) {
      int g = n >> 1, e = n & 1;
      const float* wp = W_hh + (size_t)(g * 64 + (2 * w + e) * 16 + c16) * D
                        + kk * 32 + quad * 8;
      short8 hi8, lo8;
#pragma unroll
      for (int j = 0; j < 8; ++j) {
        float v = wp[j] * gscale[g];
        unsigned short h = f2bf_rtne(v);
        hi8[j] = (short)h;
        lo8[j] = (short)f2bf_rtne(v - bf2f(h));
      }
      Bhi[kk][n] = hi8; Blo[kk][n] = lo8;
    }
  }

  float creg[8] = {0.f,0.f,0.f,0.f,0.f,0.f,0.f,0.f};   // [e*4 + r]
  float hreg[8] = {0.f,0.f,0.f,0.f,0.f,0.f,0.f,0.f};
  __syncthreads();

  int p = 0;
  for (int t4 = 0; t4 < L; t4 += 4) {
    float4 xq[4];
#pragma unroll
    for (int r = 0; r < 4; ++r)
      xq[r] = *(const float4*)&xs[(quad * 4 + r) * XSS + t4];
#pragma unroll
    for (int u = 0; u < 4; ++u) {
      // A-fragment of h(t-1): m=c16, k=kk*32+quad*8+j (single bf16)
      short8 ahi[2];
#pragma unroll
      for (int kk = 0; kk < 2; ++kk)
        ahi[kk] = *(const short8*)&hb[p][c16 * HBS + kk * 32 + quad * 8];
      float xv[4] = {xq[0][u], xq[1][u], xq[2][u], xq[3][u]};
      floatx4 acc[8];
#pragma unroll
      for (int n = 0; n < 8; ++n)
        acc[n] = (floatx4){fmaf(An[n], xv[0], Bc[n]), fmaf(An[n], xv[1], Bc[n]),
                           fmaf(An[n], xv[2], Bc[n]), fmaf(An[n], xv[3], Bc[n])};
#pragma unroll
      for (int kk = 0; kk < 2; ++kk) {
#pragma unroll
        for (int n = 0; n < 8; ++n) {
          acc[n] = __builtin_amdgcn_mfma_f32_16x16x32_bf16(ahi[kk], Bhi[kk][n], acc[n], 0, 0, 0);
          acc[n] = __builtin_amdgcn_mfma_f32_16x16x32_bf16(ahi[kk], Blo[kk][n], acc[n], 0, 0, 0);
        }
      }
      // merged elementwise: 5 exp2 + 2 rcp per cell, 8 cells in registers
#pragma unroll
      for (int e = 0; e < 2; ++e) {
#pragma unroll
        for (int r = 0; r < 4; ++r) {
          float Ei = ex2(acc[0 + e][r]);
          float Ef = ex2(acc[2 + e][r]);
          float Eg = ex2(acc[4 + e][r]);
          float Eo = ex2(acc[6 + e][r]);
          float pf = 1.0f + Ef, pi = 1.0f + Ei, pg = 1.0f + Eg;
          float mg = 1.0f - Eg;
          float pig = pi * pg;
          float num = fmaf(creg[e * 4 + r], pig, mg * pf);
          float c2  = num * fast_rcp(pf * pig);
          float Ec  = ex2(-2.0f * LOG2E * c2);
          float po = 1.0f + Eo, pc = 1.0f + Ec, mc = 1.0f - Ec;
          float h2 = mc * fast_rcp(po * pc);
          creg[e * 4 + r] = c2;
          hreg[e * 4 + r] = h2;
          int row = quad * 4 + r;
          int d = (2 * w + e) * 16 + c16;
          hb[p ^ 1][row * HBS + d] = (short)f2bf_rtne(h2);
        }
      }
      __syncthreads();
      p ^= 1;
    }
  }

  // ---- tail: h_hat = h@W_aout.T+b ; f = h_hat@W_fh.T+b ; partial sums ----
  // x tile dead: xs[row][0..63] = h fp32, xs[row][64..127] = h_hat
#pragma unroll
  for (int e = 0; e < 2; ++e)
#pragma unroll
    for (int r = 0; r < 4; ++r)
      xs[(quad * 4 + r) * XSS + (2 * w + e) * 16 + c16] = hreg[e * 4 + r];
  __syncthreads();

  float hhat[8];
#pragma unroll
  for (int e = 0; e < 2; ++e) {
    int d = (2 * w + e) * 16 + c16;
    const float4* wa = (const float4*)(W_aout + (size_t)d * D);
#pragma unroll
    for (int r = 0; r < 4; ++r) {
      float a = b_aout[d];
      const float* hp = &xs[(quad * 4 + r) * XSS];
#pragma unroll
      for (int e4 = 0; e4 < 16; ++e4) {
        float4 wv = wa[e4];
        a = fmaf(wv.x, hp[e4*4+0], a); a = fmaf(wv.y, hp[e4*4+1], a);
        a = fmaf(wv.z, hp[e4*4+2], a); a = fmaf(wv.w, hp[e4*4+3], a);
      }
      hhat[e * 4 + r] = a;
    }
  }
  __syncthreads();
#pragma unroll
  for (int e = 0; e < 2; ++e)
#pragma unroll
    for (int r = 0; r < 4; ++r)
      xs[(quad * 4 + r) * XSS + 64 + (2 * w + e) * 16 + c16] = hhat[e * 4 + r];
  __syncthreads();

  float pfc[2] = {0.f, 0.f}, phs[2] = {0.f, 0.f};
#pragma unroll
  for (int e = 0; e < 2; ++e) {
    int d = (2 * w + e) * 16 + c16;
    const float4* wf = (const float4*)(W_fh + (size_t)d * D);
#pragma unroll
    for (int r = 0; r < 4; ++r) {
      float f = b_fh[d];
      const float* hp = &xs[(quad * 4 + r) * XSS + 64];
#pragma unroll
      for (int e4 = 0; e4 < 16; ++e4) {
        float4 wv = wf[e4];
        f = fmaf(wv.x, hp[e4*4+0], f); f = fmaf(wv.y, hp[e4*4+1], f);
        f = fmaf(wv.z, hp[e4*4+2], f); f = fmaf(wv.w, hp[e4*4+3], f);
      }
      pfc[e] = fmaf(sig_plain(f), creg[e * 4 + r], pfc[e]);
      phs[e] += hhat[e * 4 + r];
    }
  }
  // reduce over quads, one atomic per (e) per c16 lane
#pragma unroll
  for (int e = 0; e < 2; ++e) {
    float a = pfc[e], b = phs[e];
    a += __shfl_xor(a, 16); a += __shfl_xor(a, 32);
    b += __shfl_xor(b, 16); b += __shfl_xor(b, 32);
    if (quad == 0) {
      int d = (2 * w + e) * 16 + c16;
      atomicAdd(acc_out + d, a);
      atomicAdd(acc_out + D + d, b);
    }
  }

  // ---- last-block finish ----
  __threadfence();
  if (tid == 0) {
    unsigned int prev = __hip_atomic_fetch_add((unsigned int*)(acc_out + 2 * D), 1u,
                                               __ATOMIC_ACQ_REL, __HIP_MEMORY_SCOPE_AGENT);
    is_last = (prev == NBLK - 1) ? 1 : 0;
  }
  __syncthreads();
  if (!is_last) return;
  __threadfence();
  if (tid < 2 * D)
    sacc[tid] = __hip_atomic_load(acc_out + tid, __ATOMIC_RELAXED, __HIP_MEMORY_SCOPE_AGENT);
  __syncthreads();
  if (tid < D) {
    const int d = tid;
    float vi = b_iouh[d], vo = b_iouh[D + d], vu = b_iouh[2 * D + d];
    for (int e = 0; e < D; ++e) {
      float hs = sacc[D + e];
      vi = fmaf(W_iouh[(size_t)d * D + e],           hs, vi);
      vo = fmaf(W_iouh[(size_t)(D + d) * D + e],     hs, vo);
      vu = fmaf(W_iouh[(size_t)(2 * D + d) * D + e], hs, vu);
    }
    float c_obj = sig_plain(vi) * tanh2(-2.0f * LOG2E * vu) + sacc[d];
    float h_obj = sig_plain(vo) * tanh2(-2.0f * LOG2E * c_obj);
    hobj[d] = h_obj;
    out[D + d] = c_obj;
  }
  __syncthreads();
  if (tid < D) {
    const int d = tid;
    float hh = b_oout[d];
    for (int e = 0; e < D; ++e) hh = fmaf(W_oout[(size_t)d * D + e], hobj[e], hh);
    out[d] = hh;
  }
}

extern "C" void kernel_launch(void* const* d_in, const int* in_sizes, int n_in,
                              void* d_out, int out_size, void* d_ws, size_t ws_size,
                              hipStream_t stream) {
  const float* x      = (const float*)d_in[0];
  const float* W_num  = (const float*)d_in[1];
  const float* b_num  = (const float*)d_in[2];
  const float* W_ih   = (const float*)d_in[3];
  const float* W_hh   = (const float*)d_in[4];
  const float* b_ih   = (const float*)d_in[5];
  const float* b_hh   = (const float*)d_in[6];
  const float* W_aout = (const float*)d_in[7];
  const float* b_aout = (const float*)d_in[8];
  const float* W_fh   = (const float*)d_in[9];
  const float* b_fh   = (const float*)d_in[10];
  const float* W_iouh = (const float*)d_in[11];
  const float* b_iouh = (const float*)d_in[12];
  const float* W_oout = (const float*)d_in[13];
  const float* b_oout = (const float*)d_in[14];
  float* acc = (float*)d_ws;
  float* out = (float*)d_out;

  hipMemsetAsync(d_ws, 0, (2 * D + 1) * sizeof(float), stream);
  lstm_main<<<NBLK, NT, 0, stream>>>(x, W_num, b_num, W_ih, W_hh, b_ih, b_hh,
                                     W_aout, b_aout, W_fh, b_fh,
                                     W_iouh, b_iouh, W_oout, b_oout, acc, out);
}

// Round 7
// 218.588 us; speedup vs baseline: 1.1275x; 1.1275x over previous
//
#include <hip/hip_runtime.h>
#include <cstddef>

#define D   64
#define L   128
#define NT  256            // 4 waves per block
#define ROWS 16            // one M=16 MFMA tile per block
#define XSS 132            // padded floats (mult of 4 keeps float4 alignment)
#define HBS 72             // shorts
#define NBLK 512           // 8192 / 16
#define LOG2E 1.4426950408889634f

typedef __attribute__((ext_vector_type(8))) short short8;
typedef __attribute__((ext_vector_type(4))) float floatx4;

__device__ __forceinline__ float fast_rcp(float x) {
#if defined(__has_builtin)
#if __has_builtin(__builtin_amdgcn_rcpf)
  return __builtin_amdgcn_rcpf(x);
#else
  return 1.0f / x;
#endif
#else
  return 1.0f / x;
#endif
}
__device__ __forceinline__ float ex2(float x) {
#if defined(__has_builtin)
#if __has_builtin(__builtin_amdgcn_exp2f)
  return __builtin_amdgcn_exp2f(x);
#else
  return __builtin_exp2f(x);
#endif
#else
  return __builtin_exp2f(x);
#endif
}
__device__ __forceinline__ float sig_plain(float x) {
  return fast_rcp(1.0f + ex2(-LOG2E * x));
}
__device__ __forceinline__ float tanh2(float G) {   // tanh(x), G = -2log2e*x
  return fmaf(2.0f, fast_rcp(1.0f + ex2(G)), -1.0f);
}
__device__ __forceinline__ unsigned short f2bf_rtne(float f) {
  unsigned int u = __float_as_uint(f);
  u += 0x7fffu + ((u >> 16) & 1u);
  return (unsigned short)(u >> 16);
}
__device__ __forceinline__ float bf2f(unsigned short s) {
  return __uint_as_float(((unsigned int)s) << 16);
}

// Persistent 16-row LSTM scan. R5 structure (empirical winner): 512 blocks x
// 4 waves -> 2 independent blocks per SIMD (anti-phased barriers give fill);
// wave w owns d in [16w,16w+16) for all 4 gates -> elementwise in registers,
// one barrier/step. 2-term MFMA split (R6-validated, absmax 0.25):
// A = rtne-bf16(h) (data-dependent rounding, averages out over 8192 rows),
// B = W_hh hi+lo exact (no systematic weight bias). Gates prescaled by
// -log2e (-2log2e for g): merged algebra = 5 exp2 + 2 rcp per cell.
__global__ __launch_bounds__(NT, 2)
void lstm_main(const float* __restrict__ x,
               const float* __restrict__ W_num,
               const float* __restrict__ b_num,
               const float* __restrict__ W_ih,
               const float* __restrict__ W_hh,
               const float* __restrict__ b_ih,
               const float* __restrict__ b_hh,
               const float* __restrict__ W_aout,
               const float* __restrict__ b_aout,
               const float* __restrict__ W_fh,
               const float* __restrict__ b_fh,
               const float* __restrict__ W_iouh,
               const float* __restrict__ b_iouh,
               const float* __restrict__ W_oout,
               const float* __restrict__ b_oout,
               float* __restrict__ acc_out,   // [0..63]=fc, [64..127]=hs, [128]=ticket
               float* __restrict__ out)
{
  __shared__ __align__(16) float xs[ROWS * XSS];       // 8.25 KB (x; later h/h_hat)
  __shared__ __align__(16) short hb[2][ROWS * HBS];    // 4.5 KB double-buffered bf16 h
  __shared__ float sacc[2 * D];
  __shared__ float hobj[D];
  __shared__ int   is_last;

  const int tid  = threadIdx.x;
  const int w    = tid >> 6;
  const int lane = tid & 63;
  const int quad = lane >> 4;
  const int c16  = lane & 15;
  const int k0   = blockIdx.x * ROWS;
  const int dcol = w * 16 + c16;

  // ---- stage x tile (16 rows x 128), coalesced ----
  for (int i = tid; i < ROWS * (L / 4); i += NT) {
    int r = i >> 5, c4 = i & 31;
    float4 v = ((const float4*)(x + (size_t)(k0 + r) * L))[c4];
    float* dst = &xs[r * XSS + c4 * 4];
    dst[0] = v.x; dst[1] = v.y; dst[2] = v.z; dst[3] = v.w;
  }
  for (int i = tid; i < ROWS * HBS; i += NT) hb[0][i] = 0;

  // per-gate exp2 prescale (g-gate feeds tanh -> -2log2e)
  const float gscale[4] = {-LOG2E, -LOG2E, -2.0f * LOG2E, -LOG2E};

  // ---- rank-1 x-projection constants (prescaled), float4 loads ----
  float An[4], Bc[4];
#pragma unroll
  for (int g = 0; g < 4; ++g) {
    int j = g * 64 + dcol;
    const float4* wr = (const float4*)(W_ih + (size_t)j * (2 * D));
    float a = 0.0f, b = b_ih[j] + b_hh[j];
#pragma unroll
    for (int e4 = 0; e4 < 16; ++e4) {
      float4 wv = wr[e4];
      float4 wn = ((const float4*)W_num)[e4];
      float4 bn = ((const float4*)b_num)[e4];
      a = fmaf(wn.x, wv.x, a); a = fmaf(wn.y, wv.y, a);
      a = fmaf(wn.z, wv.z, a); a = fmaf(wn.w, wv.w, a);
      b = fmaf(bn.x, wv.x, b); b = fmaf(bn.y, wv.y, b);
      b = fmaf(bn.z, wv.z, b); b = fmaf(bn.w, wv.w, b);
    }
    An[g] = a * gscale[g]; Bc[g] = b * gscale[g];
  }

  // ---- W_hh B-fragments (prescaled, hi+lo exact, constant across steps) ----
  short8 Bhi[4][2], Blo[4][2];
#pragma unroll
  for (int g = 0; g < 4; ++g) {
#pragma unroll
    for (int kk = 0; kk < 2; ++kk) {
      const float4* wp = (const float4*)(W_hh + (size_t)(g * 64 + dcol) * D
                                         + kk * 32 + quad * 8);
      float wv[8];
      float4 w0 = wp[0], w1 = wp[1];
      wv[0]=w0.x; wv[1]=w0.y; wv[2]=w0.z; wv[3]=w0.w;
      wv[4]=w1.x; wv[5]=w1.y; wv[6]=w1.z; wv[7]=w1.w;
      short8 hi8, lo8;
#pragma unroll
      for (int j = 0; j < 8; ++j) {
        float v = wv[j] * gscale[g];
        unsigned short h = f2bf_rtne(v);
        hi8[j] = (short)h;
        lo8[j] = (short)f2bf_rtne(v - bf2f(h));
      }
      Bhi[g][kk] = hi8; Blo[g][kk] = lo8;
    }
  }

  float creg[4] = {0.f, 0.f, 0.f, 0.f};
  float hreg[4] = {0.f, 0.f, 0.f, 0.f};
  __syncthreads();

  int p = 0;
  for (int t4 = 0; t4 < L; t4 += 4) {
    // 4 steps' worth of x per row in one b128 each
    float4 xq[4];
#pragma unroll
    for (int r = 0; r < 4; ++r)
      xq[r] = *(const float4*)&xs[(quad * 4 + r) * XSS + t4];
#pragma unroll
    for (int u = 0; u < 4; ++u) {
      // A-fragment of h(t-1): m=c16, k=kk*32+quad*8+j (single rtne-bf16)
      short8 ahi[2];
#pragma unroll
      for (int kk = 0; kk < 2; ++kk)
        ahi[kk] = *(const short8*)&hb[p][c16 * HBS + kk * 32 + quad * 8];
      float xv[4] = {xq[0][u], xq[1][u], xq[2][u], xq[3][u]};
      floatx4 acc[4];
#pragma unroll
      for (int g = 0; g < 4; ++g)
        acc[g] = (floatx4){fmaf(An[g], xv[0], Bc[g]), fmaf(An[g], xv[1], Bc[g]),
                           fmaf(An[g], xv[2], Bc[g]), fmaf(An[g], xv[3], Bc[g])};
#pragma unroll
      for (int kk = 0; kk < 2; ++kk) {
#pragma unroll
        for (int g = 0; g < 4; ++g) {
          acc[g] = __builtin_amdgcn_mfma_f32_16x16x32_bf16(ahi[kk], Bhi[g][kk], acc[g], 0, 0, 0);
          acc[g] = __builtin_amdgcn_mfma_f32_16x16x32_bf16(ahi[kk], Blo[g][kk], acc[g], 0, 0, 0);
        }
      }
      // merged elementwise: 5 exp2 + 2 rcp per cell, in registers
#pragma unroll
      for (int r = 0; r < 4; ++r) {
        float Ei = ex2(acc[0][r]);   // e^{-i}
        float Ef = ex2(acc[1][r]);   // e^{-f}
        float Eg = ex2(acc[2][r]);   // e^{-2g}
        float Eo = ex2(acc[3][r]);   // e^{-o}
        float pf = 1.0f + Ef, pi = 1.0f + Ei, pg = 1.0f + Eg;
        float mg = 1.0f - Eg;
        float pig = pi * pg;
        float num = fmaf(creg[r], pig, mg * pf);
        float c2  = num * fast_rcp(pf * pig);
        float Ec  = ex2(-2.0f * LOG2E * c2);
        float po = 1.0f + Eo, pc = 1.0f + Ec, mc = 1.0f - Ec;
        float h2 = mc * fast_rcp(po * pc);
        creg[r] = c2;
        hreg[r] = h2;
        int row = quad * 4 + r;
        hb[p ^ 1][row * HBS + dcol] = (short)f2bf_rtne(h2);
      }
      __syncthreads();
      p ^= 1;
    }
  }

  // ---- tail: h_hat = h@W_aout.T+b ; f = h_hat@W_fh.T+b ; partial sums ----
  // x tile dead: xs[row][0..63] = h fp32, xs[row][64..127] = h_hat
#pragma unroll
  for (int r = 0; r < 4; ++r) xs[(quad * 4 + r) * XSS + dcol] = hreg[r];
  __syncthreads();

  float hhat[4];
#pragma unroll
  for (int r = 0; r < 4; ++r) {
    float a = b_aout[dcol];
    const float4* wa = (const float4*)(W_aout + (size_t)dcol * D);
    const float* hp = &xs[(quad * 4 + r) * XSS];
#pragma unroll
    for (int e4 = 0; e4 < 16; ++e4) {
      float4 wv = wa[e4];
      a = fmaf(wv.x, hp[e4*4+0], a); a = fmaf(wv.y, hp[e4*4+1], a);
      a = fmaf(wv.z, hp[e4*4+2], a); a = fmaf(wv.w, hp[e4*4+3], a);
    }
    hhat[r] = a;
  }
  __syncthreads();
#pragma unroll
  for (int r = 0; r < 4; ++r) xs[(quad * 4 + r) * XSS + 64 + dcol] = hhat[r];
  __syncthreads();

  float pfc = 0.0f, phs = 0.0f;
#pragma unroll
  for (int r = 0; r < 4; ++r) {
    float f = b_fh[dcol];
    const float4* wf = (const float4*)(W_fh + (size_t)dcol * D);
    const float* hp = &xs[(quad * 4 + r) * XSS + 64];
#pragma unroll
    for (int e4 = 0; e4 < 16; ++e4) {
      float4 wv = wf[e4];
      f = fmaf(wv.x, hp[e4*4+0], f); f = fmaf(wv.y, hp[e4*4+1], f);
      f = fmaf(wv.z, hp[e4*4+2], f); f = fmaf(wv.w, hp[e4*4+3], f);
    }
    pfc = fmaf(sig_plain(f), creg[r], pfc);
    phs += hhat[r];
  }
  pfc += __shfl_xor(pfc, 16); pfc += __shfl_xor(pfc, 32);
  phs += __shfl_xor(phs, 16); phs += __shfl_xor(phs, 32);
  if (quad == 0) {
    atomicAdd(acc_out + dcol, pfc);
    atomicAdd(acc_out + D + dcol, phs);
  }

  // ---- last-block finish ----
  __threadfence();
  if (tid == 0) {
    unsigned int prev = __hip_atomic_fetch_add((unsigned int*)(acc_out + 2 * D), 1u,
                                               __ATOMIC_ACQ_REL, __HIP_MEMORY_SCOPE_AGENT);
    is_last = (prev == NBLK - 1) ? 1 : 0;
  }
  __syncthreads();
  if (!is_last) return;
  __threadfence();
  if (tid < 2 * D)
    sacc[tid] = __hip_atomic_load(acc_out + tid, __ATOMIC_RELAXED, __HIP_MEMORY_SCOPE_AGENT);
  __syncthreads();
  if (tid < D) {
    const int d = tid;
    float vi = b_iouh[d], vo = b_iouh[D + d], vu = b_iouh[2 * D + d];
    for (int e = 0; e < D; ++e) {
      float hs = sacc[D + e];
      vi = fmaf(W_iouh[(size_t)d * D + e],           hs, vi);
      vo = fmaf(W_iouh[(size_t)(D + d) * D + e],     hs, vo);
      vu = fmaf(W_iouh[(size_t)(2 * D + d) * D + e], hs, vu);
    }
    float c_obj = sig_plain(vi) * tanh2(-2.0f * LOG2E * vu) + sacc[d];
    float h_obj = sig_plain(vo) * tanh2(-2.0f * LOG2E * c_obj);
    hobj[d] = h_obj;
    out[D + d] = c_obj;
  }
  __syncthreads();
  if (tid < D) {
    const int d = tid;
    float hh = b_oout[d];
    for (int e = 0; e < D; ++e) hh = fmaf(W_oout[(size_t)d * D + e], hobj[e], hh);
    out[d] = hh;
  }
}

extern "C" void kernel_launch(void* const* d_in, const int* in_sizes, int n_in,
                              void* d_out, int out_size, void* d_ws, size_t ws_size,
                              hipStream_t stream) {
  const float* x      = (const float*)d_in[0];
  const float* W_num  = (const float*)d_in[1];
  const float* b_num  = (const float*)d_in[2];
  const float* W_ih   = (const float*)d_in[3];
  const float* W_hh   = (const float*)d_in[4];
  const float* b_ih   = (const float*)d_in[5];
  const float* b_hh   = (const float*)d_in[6];
  const float* W_aout = (const float*)d_in[7];
  const float* b_aout = (const float*)d_in[8];
  const float* W_fh   = (const float*)d_in[9];
  const float* b_fh   = (const float*)d_in[10];
  const float* W_iouh = (const float*)d_in[11];
  const float* b_iouh = (const float*)d_in[12];
  const float* W_oout = (const float*)d_in[13];
  const float* b_oout = (const float*)d_in[14];
  float* acc = (float*)d_ws;
  float* out = (float*)d_out;

  hipMemsetAsync(d_ws, 0, (2 * D + 1) * sizeof(float), stream);
  lstm_main<<<NBLK, NT, 0, stream>>>(x, W_num, b_num, W_ih, W_hh, b_ih, b_hh,
                                     W_aout, b_aout, W_fh, b_fh,
                                     W_iouh, b_iouh, W_oout, b_oout, acc, out);
}